// Round 1
// baseline (602.554 us; speedup 1.0000x reference)
//
#include <hip/hip_runtime.h>
#include <hip/hip_fp16.h>

// ---- problem constants ----
#define BTOK  4096
#define D_IN  1024
#define D_HID 4096
#define D_OUT 1024
#define NE    8
#define PT_MAX 72          // max padded pair tiles (8192/128 + 8)
#define P_MAX  9216        // PT_MAX*128
#define KT1   32           // gemm1 K-chunks (1024/32)
#define NT1M  32           // gemm1 N-tiles merged (4096/128)
#define KT2M  128          // gemm2 K-chunks merged (4096/32)
#define NT2   8            // gemm2 N-tiles (1024/128)
#define GB    256          // gating blocks

typedef _Float16 half8 __attribute__((ext_vector_type(8)));
typedef _Float16 half4v __attribute__((ext_vector_type(4)));
typedef float    floatx4 __attribute__((ext_vector_type(4)));

// ---- ws layout (bytes), total ~236 MiB (ws poison fill shows 512 MiB available) ----
// xt   : f16 x tiles   [72][32][128x32]      @ 0            (18,874,368)
// W1t  : f16 W1 tiles  [8][32][32][128x32]   @ 18,874,368   (67,108,864)
// W2t  : f16 W2 tiles  [8][8][128][128x32]   @ 85,983,232   (67,108,864)
// ht   : f16 h tiles   [72][128][128x32]     @ 153,092,096  (75,497,472)
// y    : f16 y         [9216][1024]          @ 228,589,568  (18,874,368)
// t2i  : int [8192]                          @ 247,463,936  (32,768)
// t2w  : f32 [8192]                          @ 247,496,704  (32,768)
// ptok : int [9216]                          @ 247,529,472  (36,864)
// pslot: int [8192]                          @ 247,566,336  (32,768)
// meta : cnt8,cur8,offs8,tile2e72,ntiles     @ 247,599,104  (512)
// pcnt : int  [256*8]                        @ 247,599,616  (8,192)
// pusage: f32 [256*8]                        @ 247,607,808  (8,192)

__device__ __forceinline__ void g2l16(const void* g, void* s) {
    __builtin_amdgcn_global_load_lds((const __attribute__((address_space(1))) void*)g,
                                     (__attribute__((address_space(3))) void*)s, 16, 0, 0);
}

// ---------------- gating: fp64 logits, top-2, softmax; LDS-aggregated partials ----------------
__global__ __launch_bounds__(256)
void gating_kernel(const float* __restrict__ x, const float* __restrict__ Wg,
                   const float* __restrict__ bg,
                   int* __restrict__ t2i, float* __restrict__ t2w,
                   int* __restrict__ pcnt, float* __restrict__ pusage) {
    __shared__ float wgT[NE * 1024];   // transposed gate weights: [e][i]
    __shared__ float susage[NE];
    __shared__ int   scnt[NE];
    int tid = threadIdx.x;
    if (tid < NE) { susage[tid] = 0.f; scnt[tid] = 0; }
    #pragma unroll
    for (int k = 0; k < 8192; k += 256) {
        int idx = k + tid;
        wgT[(idx & 7) * 1024 + (idx >> 3)] = Wg[idx];
    }
    __syncthreads();
    int wv = tid >> 6, lane = tid & 63;
    for (int tt = 0; tt < 4; ++tt) {
        int t = blockIdx.x * 16 + wv * 4 + tt;
        double part[NE];
        #pragma unroll
        for (int e = 0; e < NE; ++e) part[e] = 0.0;
        #pragma unroll
        for (int j = 0; j < 16; ++j) {
            int i = j * 64 + lane;
            double xv = (double)x[(size_t)t * D_IN + i];
            #pragma unroll
            for (int e = 0; e < NE; ++e) part[e] += xv * (double)wgT[e * 1024 + i];
        }
        #pragma unroll
        for (int e = 0; e < NE; ++e) {
            #pragma unroll
            for (int s = 32; s > 0; s >>= 1) part[e] += __shfl_xor(part[e], s, 64);
        }
        if (lane == 0) {
            float l[NE];
            #pragma unroll
            for (int e = 0; e < NE; ++e) l[e] = (float)part[e] + bg[e];
            float M = l[0];
            #pragma unroll
            for (int e = 1; e < NE; ++e) M = fmaxf(M, l[e]);
            float s = 0.f, g[NE];
            #pragma unroll
            for (int e = 0; e < NE; ++e) { g[e] = __expf(l[e] - M); s += g[e]; }
            float inv = 1.f / s;
            #pragma unroll
            for (int e = 0; e < NE; ++e) atomicAdd(&susage[e], g[e] * inv);
            int i0 = 0; float b0 = l[0];
            #pragma unroll
            for (int e = 1; e < NE; ++e) if (l[e] > b0) { b0 = l[e]; i0 = e; }
            int i1 = -1; float b1v = -1e30f;
            #pragma unroll
            for (int e = 0; e < NE; ++e) if (e != i0 && l[e] > b1v) { b1v = l[e]; i1 = e; }
            float w0 = 1.f / (1.f + expf(b1v - b0));
            t2i[2 * t] = i0; t2i[2 * t + 1] = i1;
            t2w[2 * t] = w0; t2w[2 * t + 1] = 1.f - w0;
            atomicAdd(&scnt[i0], 1);
            atomicAdd(&scnt[i1], 1);
        }
    }
    __syncthreads();
    if (tid < NE) {
        pcnt[blockIdx.x * NE + tid] = scnt[tid];
        pusage[blockIdx.x * NE + tid] = susage[tid];
    }
}

// ---------------- scan: reduce partials, padded offsets, tile->expert map, loss ----------------
__global__ void scan_kernel(const int* __restrict__ pcnt, const float* __restrict__ pusage,
                            int* __restrict__ meta, float* __restrict__ out_loss) {
    int lane = threadIdx.x;           // 64 threads
    int e = lane & 7, b0 = lane >> 3;
    int c = 0; float u = 0.f;
    for (int b = b0; b < GB; b += 8) { c += pcnt[b * 8 + e]; u += pusage[b * 8 + e]; }
    #pragma unroll
    for (int s = 8; s < 64; s <<= 1) { c += __shfl_xor(c, s, 64); u += __shfl_xor(u, s, 64); }
    int cAll[NE]; float uAll[NE];
    #pragma unroll
    for (int q = 0; q < NE; ++q) { cAll[q] = __shfl(c, q, 64); uAll[q] = __shfl(u, q, 64); }
    if (lane == 0) {
        int* cnt = meta; int* cursor = meta + 8; int* offs = meta + 16;
        int* tile2e = meta + 24; int* ntiles = meta + 96;
        int run = 0;
        for (int q = 0; q < NE; ++q) {
            cnt[q] = cAll[q];
            offs[q] = run; cursor[q] = run;
            int ntl = (cAll[q] + 127) >> 7;
            int tb = run >> 7;
            for (int i = 0; i < ntl; ++i) tile2e[tb + i] = q;
            run += ntl << 7;
        }
        ntiles[0] = run >> 7;
        float loss = 0.f;
        for (int q = 0; q < NE; ++q) { float uu = uAll[q] / (float)BTOK; loss += uu * uu; }
        out_loss[0] = (float)NE * loss;
    }
}

// ---------------- fill padded slots with token 0 ----------------
__global__ void fill_kernel(int* __restrict__ ptok) {
    ptok[blockIdx.x * 256 + threadIdx.x] = 0;
}

// ---------------- scatter: LDS-aggregated slot assignment ----------------
__global__ void scatter_kernel(const int* __restrict__ t2i, int* __restrict__ cursor,
                               int* __restrict__ ptok, int* __restrict__ pslot) {
    __shared__ int lcnt[NE], base[NE];
    int tid = threadIdx.x;
    if (tid < NE) lcnt[tid] = 0;
    __syncthreads();
    int t = blockIdx.x * 256 + tid;
    int e0 = t2i[2 * t], e1 = t2i[2 * t + 1];
    int l0 = atomicAdd(&lcnt[e0], 1);
    int l1 = atomicAdd(&lcnt[e1], 1);
    __syncthreads();
    if (tid < NE) base[tid] = atomicAdd(&cursor[tid], lcnt[tid]);
    __syncthreads();
    int s0 = base[e0] + l0, s1 = base[e1] + l1;
    ptok[s0] = t; ptok[s1] = t;
    pslot[2 * t] = s0; pslot[2 * t + 1] = s1;
}

// ---------------- gather x into tiled fp16 [ptile][k0][128x32] ----------------
__global__ void gather_x_kernel(const float* __restrict__ x, const int* __restrict__ ptok,
                                _Float16* __restrict__ xt) {
    int k0 = blockIdx.x, ptile = blockIdx.y;
    int t = threadIdx.x;
    int m = t >> 1, kb = (t & 1) * 16;
    int tok = ptok[ptile * 128 + m];
    const float* src = x + (size_t)tok * D_IN + k0 * 32 + kb;
    float4 v0 = *(const float4*)(src);
    float4 v1 = *(const float4*)(src + 4);
    float4 v2 = *(const float4*)(src + 8);
    float4 v3 = *(const float4*)(src + 12);
    half8 o0, o1;
    o0[0]=(_Float16)v0.x; o0[1]=(_Float16)v0.y; o0[2]=(_Float16)v0.z; o0[3]=(_Float16)v0.w;
    o0[4]=(_Float16)v1.x; o0[5]=(_Float16)v1.y; o0[6]=(_Float16)v1.z; o0[7]=(_Float16)v1.w;
    o1[0]=(_Float16)v2.x; o1[1]=(_Float16)v2.y; o1[2]=(_Float16)v2.z; o1[3]=(_Float16)v2.w;
    o1[4]=(_Float16)v3.x; o1[5]=(_Float16)v3.y; o1[6]=(_Float16)v3.z; o1[7]=(_Float16)v3.w;
    _Float16* dst = xt + ((size_t)ptile * KT1 + k0) * 4096 + t * 16;
    *(half8*)dst = o0;
    *(half8*)(dst + 8) = o1;
}

// ---------------- W [e][Ktot][Ntot] f32 -> tiles [e][nt][k0][128x32] f16 ----------------
__global__ void wtile_kernel(const float* __restrict__ W, _Float16* __restrict__ Wt,
                             int Ktot, int Ntot, int KT, int NT) {
    int k0 = blockIdx.x, ntb = blockIdx.y, e = blockIdx.z;
    int t = threadIdx.x;
    int nl = t >> 1, kb = (t & 1) * 16;
    const float* src = W + ((size_t)e * Ktot + k0 * 32 + kb) * Ntot + ntb * 128 + nl;
    float v[16];
    #pragma unroll
    for (int j = 0; j < 16; ++j) v[j] = src[(size_t)j * Ntot];
    half8 o0, o1;
    #pragma unroll
    for (int j = 0; j < 8; ++j) { o0[j] = (_Float16)v[j]; o1[j] = (_Float16)v[j + 8]; }
    _Float16* dst = Wt + (((size_t)e * NT + ntb) * KT + k0) * 4096 + t * 16;
    *(half8*)dst = o0;
    *(half8*)(dst + 8) = o1;
}

// ---------------- GEMM1 (2-phase dbuf): ht = relu(xt @ W1t^T + b1), N=4096 merged ----------------
__global__ __launch_bounds__(256, 3)
void gemm1_kernel(const _Float16* __restrict__ xt, const _Float16* __restrict__ W1t,
                  const float* __restrict__ b1, _Float16* __restrict__ ht,
                  const int* __restrict__ meta) {
    int ptile = blockIdx.x;
    if (ptile >= meta[96]) return;
    int nt = blockIdx.y;
    int e = meta[24 + ptile];

    __shared__ __align__(16) _Float16 Asm[2][128 * 32];
    __shared__ __align__(16) _Float16 Bsm[2][128 * 32];

    int tid = threadIdx.x;
    int wave = tid >> 6, lane = tid & 63;
    const _Float16* Abase = xt + (size_t)ptile * KT1 * 4096;
    const _Float16* Bbase = W1t + ((size_t)(e * NT1M + nt) * KT1) * 4096;
    int stg = wave * 512 + lane * 8;

    floatx4 acc[4][4] = {};
    int lr = lane & 15, lq = lane >> 4;
    int wm = (wave & 1) * 64, wn = (wave >> 1) * 64;

    // prologue: stage k0=0 into buffer 0
    g2l16(Abase + stg,        &Asm[0][wave * 512]);
    g2l16(Abase + stg + 2048, &Asm[0][wave * 512 + 2048]);
    g2l16(Bbase + stg,        &Bsm[0][wave * 512]);
    g2l16(Bbase + stg + 2048, &Bsm[0][wave * 512 + 2048]);
    __syncthreads();

    int ct = 0;
    for (int k0 = 0; k0 < KT1; ++k0) {
        // issue next-tile staging BEFORE compute (overlaps with ds_read+MFMA)
        if (k0 + 1 < KT1) {
            const _Float16* aG = Abase + (size_t)(k0 + 1) * 4096 + stg;
            const _Float16* bG = Bbase + (size_t)(k0 + 1) * 4096 + stg;
            int nb = ct ^ 1;
            g2l16(aG,        &Asm[nb][wave * 512]);
            g2l16(aG + 2048, &Asm[nb][wave * 512 + 2048]);
            g2l16(bG,        &Bsm[nb][wave * 512]);
            g2l16(bG + 2048, &Bsm[nb][wave * 512 + 2048]);
        }
        const _Float16* As = Asm[ct];
        const _Float16* Bs = Bsm[ct];
        half8 af[4], bf[4];
        #pragma unroll
        for (int f = 0; f < 4; ++f) {
            af[f] = *(const half8*)&As[(wm + f * 16 + lr) * 32 + lq * 8];
            bf[f] = *(const half8*)&Bs[(wn + f * 16 + lr) * 32 + lq * 8];
        }
        #pragma unroll
        for (int mf = 0; mf < 4; ++mf)
            #pragma unroll
            for (int nf = 0; nf < 4; ++nf)
                acc[mf][nf] = __builtin_amdgcn_mfma_f32_16x16x32_f16(af[mf], bf[nf], acc[mf][nf], 0, 0, 0);
        __syncthreads();   // drains staged loads; next iter's buffer ready
        ct ^= 1;
    }

    const float* b1e = b1 + (size_t)e * D_HID;
    #pragma unroll
    for (int mf = 0; mf < 4; ++mf) {
        #pragma unroll
        for (int v = 0; v < 4; ++v) {
            int m = wm + mf * 16 + lq * 4 + v;
            #pragma unroll
            for (int nf = 0; nf < 4; ++nf) {
                int hl = nt * 128 + wn + nf * 16 + lr;
                float val = acc[mf][nf][v] + b1e[hl];
                ht[((size_t)ptile * KT2M + (hl >> 5)) * 4096 + m * 32 + (hl & 31)]
                    = (_Float16)fmaxf(val, 0.f);
            }
        }
    }
}

// ---------------- GEMM2 (2-phase dbuf): y = ht @ W2t^T, K=4096 merged ----------------
__global__ __launch_bounds__(256, 3)
void gemm2_kernel(const _Float16* __restrict__ ht, const _Float16* __restrict__ W2t,
                  _Float16* __restrict__ y, const int* __restrict__ meta) {
    int ptile = blockIdx.x;
    if (ptile >= meta[96]) return;
    int nt = blockIdx.y;
    int e = meta[24 + ptile];

    __shared__ __align__(16) _Float16 Asm[2][128 * 32];
    __shared__ __align__(16) _Float16 Bsm[2][128 * 32];

    int tid = threadIdx.x;
    int wave = tid >> 6, lane = tid & 63;
    const _Float16* Abase = ht + (size_t)ptile * KT2M * 4096;
    const _Float16* Bbase = W2t + ((size_t)(e * NT2 + nt) * KT2M) * 4096;
    int stg = wave * 512 + lane * 8;

    floatx4 acc[4][4] = {};
    int lr = lane & 15, lq = lane >> 4;
    int wm = (wave & 1) * 64, wn = (wave >> 1) * 64;

    g2l16(Abase + stg,        &Asm[0][wave * 512]);
    g2l16(Abase + stg + 2048, &Asm[0][wave * 512 + 2048]);
    g2l16(Bbase + stg,        &Bsm[0][wave * 512]);
    g2l16(Bbase + stg + 2048, &Bsm[0][wave * 512 + 2048]);
    __syncthreads();

    int ct = 0;
    for (int k0 = 0; k0 < KT2M; ++k0) {
        if (k0 + 1 < KT2M) {
            const _Float16* aG = Abase + (size_t)(k0 + 1) * 4096 + stg;
            const _Float16* bG = Bbase + (size_t)(k0 + 1) * 4096 + stg;
            int nb = ct ^ 1;
            g2l16(aG,        &Asm[nb][wave * 512]);
            g2l16(aG + 2048, &Asm[nb][wave * 512 + 2048]);
            g2l16(bG,        &Bsm[nb][wave * 512]);
            g2l16(bG + 2048, &Bsm[nb][wave * 512 + 2048]);
        }
        const _Float16* As = Asm[ct];
        const _Float16* Bs = Bsm[ct];
        half8 af[4], bf[4];
        #pragma unroll
        for (int f = 0; f < 4; ++f) {
            af[f] = *(const half8*)&As[(wm + f * 16 + lr) * 32 + lq * 8];
            bf[f] = *(const half8*)&Bs[(wn + f * 16 + lr) * 32 + lq * 8];
        }
        #pragma unroll
        for (int mf = 0; mf < 4; ++mf)
            #pragma unroll
            for (int nf = 0; nf < 4; ++nf)
                acc[mf][nf] = __builtin_amdgcn_mfma_f32_16x16x32_f16(af[mf], bf[nf], acc[mf][nf], 0, 0, 0);
        __syncthreads();
        ct ^= 1;
    }

    #pragma unroll
    for (int mf = 0; mf < 4; ++mf) {
        #pragma unroll
        for (int v = 0; v < 4; ++v) {
            int m = wm + mf * 16 + lq * 4 + v;
            #pragma unroll
            for (int nf = 0; nf < 4; ++nf) {
                int c = nt * 128 + wn + nf * 16 + lr;
                y[(size_t)(ptile * 128 + m) * D_OUT + c] = (_Float16)acc[mf][nf][v];
            }
        }
    }
}

// ---------------- combine: out[t] = sum_k w_k * (y[slot_k] + b2[e_k]) ----------------
__global__ void combine_kernel(const _Float16* __restrict__ y, const float* __restrict__ b2,
                               const int* __restrict__ t2i, const float* __restrict__ t2w,
                               const int* __restrict__ pslot, float* __restrict__ out) {
    int t = blockIdx.x;
    int c = threadIdx.x * 4;
    int e0 = t2i[2 * t], e1 = t2i[2 * t + 1];
    float w0 = t2w[2 * t], w1 = t2w[2 * t + 1];
    size_t s0 = (size_t)pslot[2 * t] * D_OUT + c;
    size_t s1 = (size_t)pslot[2 * t + 1] * D_OUT + c;
    half4v a0 = *(const half4v*)(y + s0);
    half4v a1 = *(const half4v*)(y + s1);
    float4 bias0 = *(const float4*)(b2 + (size_t)e0 * D_OUT + c);
    float4 bias1 = *(const float4*)(b2 + (size_t)e1 * D_OUT + c);
    float4 o;
    o.x = w0 * ((float)a0[0] + bias0.x) + w1 * ((float)a1[0] + bias1.x);
    o.y = w0 * ((float)a0[1] + bias0.y) + w1 * ((float)a1[1] + bias1.y);
    o.z = w0 * ((float)a0[2] + bias0.z) + w1 * ((float)a1[2] + bias1.z);
    o.w = w0 * ((float)a0[3] + bias0.w) + w1 * ((float)a1[3] + bias1.w);
    *(float4*)(out + (size_t)t * D_OUT + c) = o;
}

extern "C" void kernel_launch(void* const* d_in, const int* in_sizes, int n_in,
                              void* d_out, int out_size, void* d_ws, size_t ws_size,
                              hipStream_t stream) {
    const float* x  = (const float*)d_in[0];
    const float* Wg = (const float*)d_in[1];
    const float* bg = (const float*)d_in[2];
    const float* W1 = (const float*)d_in[3];
    const float* b1 = (const float*)d_in[4];
    const float* W2 = (const float*)d_in[5];
    const float* b2 = (const float*)d_in[6];
    float* out = (float*)d_out;

    char* ws = (char*)d_ws;
    _Float16* xt     = (_Float16*)(ws);
    _Float16* W1t    = (_Float16*)(ws + 18874368ull);
    _Float16* W2t    = (_Float16*)(ws + 85983232ull);
    _Float16* ht     = (_Float16*)(ws + 153092096ull);
    _Float16* y      = (_Float16*)(ws + 228589568ull);
    int*      t2i    = (int*)(ws + 247463936ull);
    float*    t2w    = (float*)(ws + 247496704ull);
    int*      ptok   = (int*)(ws + 247529472ull);
    int*      pslot  = (int*)(ws + 247566336ull);
    int*      meta   = (int*)(ws + 247599104ull);
    int*      pcnt   = (int*)(ws + 247599616ull);
    float*    pusage = (float*)(ws + 247607808ull);
    int* cursor = meta + 8;

    hipMemsetAsync(meta, 0, 512, stream);

    gating_kernel<<<GB, 256, 0, stream>>>(x, Wg, bg, t2i, t2w, pcnt, pusage);
    scan_kernel<<<1, 64, 0, stream>>>(pcnt, pusage, meta, out + (size_t)BTOK * D_OUT);
    fill_kernel<<<36, 256, 0, stream>>>(ptok);
    scatter_kernel<<<16, 256, 0, stream>>>(t2i, cursor, ptok, pslot);
    gather_x_kernel<<<dim3(KT1, PT_MAX), 256, 0, stream>>>(x, ptok, xt);

    // full weight tiling (no half-split; W1t/W2t are separate buffers)
    wtile_kernel<<<dim3(KT1, NT1M, 8), 256, 0, stream>>>(W1, W1t, D_IN, D_HID, KT1, NT1M);
    wtile_kernel<<<dim3(KT2M, NT2, 8), 256, 0, stream>>>(W2, W2t, D_HID, D_OUT, KT2M, NT2);

    gemm1_kernel<<<dim3(PT_MAX, NT1M), 256, 0, stream>>>(xt, W1t, b1, ht, meta);
    gemm2_kernel<<<dim3(PT_MAX, NT2), 256, 0, stream>>>(ht, W2t, y, meta);

    combine_kernel<<<BTOK, 256, 0, stream>>>(y, b2, t2i, t2w, pslot, out);
}